// Round 9
// baseline (105.402 us; speedup 1.0000x reference)
//
#include <hip/hip_runtime.h>
#include <hip/hip_fp16.h>

#define DIM 33
#define D2  (DIM*DIM)            // 1089
#define D3  (DIM*DIM*DIM)        // 35937
#define CH3 (3*D3)               // 107811
#define NUM 20
#define BATCH 4
#define IMG_H 1080
#define IMG_W 1920
#define HW (IMG_H*IMG_W)         // 2073600
#define FAKES_SIZE (BATCH*3*HW)  // 24883200
#define D3LUT_SIZE (BATCH*CH3)   // 431244
#define NCELL 32
#define CELLS (NCELL*NCELL*NCELL) // 32768
#define TEX_BYTES ((size_t)BATCH * CELLS * 32)   // 4.19 MB
#define PACK_BLOCKS 512                          // BATCH*CELLS / 256
#define MIX_BLOCKS ((BATCH * CH3 + 255) / 256)   // 1685
#define PREP_BLOCKS (PACK_BLOCKS + MIX_BLOCKS)   // 2197
#define TRI_PIX_BLOCKS (BATCH * HW / 2 / 256)    // 16200 exactly

typedef float f32x2 __attribute__((ext_vector_type(2)));

// ---------------------------------------------------------------------------
// Kernel 1 (fused prep):
//   blocks [0, PACK_BLOCKS):       pack 32B cells directly from luts+weights
//   blocks [PACK_BLOCKS, PREP):    mix -> d3lut (output)
//   all blocks:                    TVMN partial sums (grid-stride)
// ---------------------------------------------------------------------------
__global__ void prep_kernel(const float* __restrict__ w,
                            const float* __restrict__ luts,
                            float* __restrict__ d3lut,
                            unsigned int* __restrict__ tex,
                            float* __restrict__ partials) {
    int blk = blockIdx.x;
    int t = blk * blockDim.x + threadIdx.x;

    if (blk < PACK_BLOCKS) {
        // ---- pack path: one thread per cell, recompute 24 mixed corners ----
        int b = t >> 15;
        int cidx = t & (CELLS - 1);
        int bid = cidx >> 10;
        int gid = (cidx >> 5) & 31;
        int rid = cidx & 31;
        int base = bid * D2 + gid * DIM + rid;

        float v[24];
#pragma unroll
        for (int i = 0; i < 24; ++i) v[i] = 0.f;

#pragma unroll
        for (int n = 0; n < NUM; ++n) {
            float wn = w[b * NUM + n];
            const float* Ln = luts + (size_t)n * CH3 + base;
#pragma unroll
            for (int cr = 0; cr < 8; ++cr) {
                int off = (cr >> 2) * D2 + ((cr >> 1) & 1) * DIM + (cr & 1);
#pragma unroll
                for (int c = 0; c < 3; ++c)
                    v[cr * 3 + c] += wn * Ln[(size_t)c * D3 + off];
            }
        }

        float amax = 0.f;
#pragma unroll
        for (int i = 0; i < 24; ++i) amax = fmaxf(amax, fabsf(v[i]));

        float s = amax * (1.0f / 511.0f);
        __half sh = __float2half(s);
        float sf = __half2float(sh);
        float inv = sf > 0.f ? 1.0f / sf : 0.f;

        unsigned int wq[8] = {0, 0, 0, 0, 0, 0, 0, 0};
#pragma unroll
        for (int i = 0; i < 24; ++i) {
            int m = (int)rintf(v[i] * inv);
            m = m > 511 ? 511 : (m < -511 ? -511 : m);
            unsigned int u = (unsigned int)(m + 512);
            int off = 10 * i;
            int dw = off >> 5, shl = off & 31;
            wq[dw] |= u << shl;
            if (shl > 22) wq[dw + 1] |= u >> (32 - shl);
        }
        wq[7] |= ((unsigned int)__half_as_ushort(sh)) << 16;

        uint4* dst = reinterpret_cast<uint4*>(tex + (size_t)t * 8);
        dst[0] = make_uint4(wq[0], wq[1], wq[2], wq[3]);
        dst[1] = make_uint4(wq[4], wq[5], wq[6], wq[7]);
    } else {
        // ---- mix path: one thread per d3lut element ----
        int m = t - PACK_BLOCKS * 256;
        if (m < BATCH * CH3) {
            int b = m / CH3;
            int i = m - b * CH3;
            float acc = 0.f;
#pragma unroll
            for (int n = 0; n < NUM; ++n)
                acc += w[b * NUM + n] * luts[(size_t)n * CH3 + i];
            d3lut[m] = acc;
        }
    }

    // ---- TVMN partials: grid-stride over all LUT elements ----
    const int total = NUM * 3 * D3;
    float s0 = 0.f, s1 = 0.f;
    for (int idx = t; idx < total; idx += gridDim.x * blockDim.x) {
        int k  = idx % DIM;
        int r1 = idx / DIM;
        int j  = r1 % DIM;
        int r2 = r1 / DIM;
        int i  = r2 % DIM;
        float v = luts[idx];
        if (k < DIM - 1) {
            float dif = v - luts[idx + 1];
            float ww = (k == 0 || k == DIM - 2) ? 2.f : 1.f;
            s0 += ww * dif * dif;
            float rp = dif > 0.f ? dif : 0.f;
            s1 += (ww * rp) * (ww * rp);
        }
        if (j < DIM - 1) {
            float dif = v - luts[idx + DIM];
            float ww = (j == 0 || j == DIM - 2) ? 2.f : 1.f;
            s0 += ww * dif * dif;
            float rp = dif > 0.f ? dif : 0.f;
            s1 += (ww * rp) * (ww * rp);
        }
        if (i < DIM - 1) {
            float dif = v - luts[idx + D2];
            float ww = (i == 0 || i == DIM - 2) ? 2.f : 1.f;
            s0 += ww * dif * dif;
            float rp = dif > 0.f ? dif : 0.f;
            s1 += (ww * rp) * (ww * rp);
        }
    }
#pragma unroll
    for (int off = 32; off > 0; off >>= 1) {
        s0 += __shfl_down(s0, off, 64);
        s1 += __shfl_down(s1, off, 64);
    }
    __shared__ float sh0[4], sh1[4];
    int wid = threadIdx.x >> 6, lane = threadIdx.x & 63;
    if (lane == 0) { sh0[wid] = s0; sh1[wid] = s1; }
    __syncthreads();
    if (threadIdx.x == 0) {
        partials[2 * blockIdx.x]     = sh0[0] + sh0[1] + sh0[2] + sh0[3];
        partials[2 * blockIdx.x + 1] = sh1[0] + sh1[1] + sh1[2] + sh1[3];
    }
}

// ---------------------------------------------------------------------------
// Kernel 2: trilerp, 2 pixels/thread, XCD swizzle. One extra block does the
// TVMN final reduce.
// ---------------------------------------------------------------------------
__device__ __forceinline__ int xcd_swizzle(int blk, int nwg) {
    int q = nwg >> 3, r = nwg & 7;
    int xcd = blk & 7, idx = blk >> 3;
    int base = (xcd < r) ? xcd * (q + 1) : r * (q + 1) + (xcd - r) * q;
    return base + idx;
}

__device__ __forceinline__ void trilerp_one(const unsigned int* __restrict__ tex,
                                            int b, float r, float g, float bl,
                                            float* o0, float* o1, float* o2) {
    const float INVBIN = (float)(DIM - 1) / 1.000001f;
    float fr = r * INVBIN, fg = g * INVBIN, fb = bl * INVBIN;
    int rid = (int)fr, gid = (int)fg, bid = (int)fb;
    float rd = fr - (float)rid;
    float gd = fg - (float)gid;
    float bd = fb - (float)bid;

    size_t cell = (((size_t)b * NCELL + bid) * NCELL + gid) * NCELL + rid;
    const uint4* cp = reinterpret_cast<const uint4*>(tex + cell * 8);
    uint4 q0 = cp[0];
    uint4 q1 = cp[1];
    unsigned int w[8] = {q0.x, q0.y, q0.z, q0.w, q1.x, q1.y, q1.z, q1.w};

    float s = __half2float(__ushort_as_half((unsigned short)(w[7] >> 16)));
    float c512 = 512.f * s;

    float r0 = 1.f - rd, g0 = 1.f - gd, b0 = 1.f - bd;
    float wgt[8];
    wgt[0] = b0 * g0 * r0; wgt[1] = b0 * g0 * rd;
    wgt[2] = b0 * gd * r0; wgt[3] = b0 * gd * rd;
    wgt[4] = bd * g0 * r0; wgt[5] = bd * g0 * rd;
    wgt[6] = bd * gd * r0; wgt[7] = bd * gd * rd;

    float a0 = 0.f, a1 = 0.f, a2 = 0.f;
#pragma unroll
    for (int cr = 0; cr < 8; ++cr) {
#pragma unroll
        for (int c = 0; c < 3; ++c) {
            int i = cr * 3 + c;
            int off = 10 * i;
            int dw = off >> 5, shl = off & 31;
            unsigned int u = w[dw] >> shl;
            if (shl > 22) u |= w[dw + 1] << (32 - shl);
            u &= 1023u;
            float val = fmaf((float)u, s, -c512);
            if (c == 0) a0 += wgt[cr] * val;
            else if (c == 1) a1 += wgt[cr] * val;
            else a2 += wgt[cr] * val;
        }
    }
    *o0 = a0 + r; *o1 = a1 + g; *o2 = a2 + bl;
}

__global__ void trilerp_cell_kernel(const float* __restrict__ img,
                                    const unsigned int* __restrict__ tex,
                                    float* __restrict__ out,
                                    const float* __restrict__ partials,
                                    float* __restrict__ loss) {
    int blk = xcd_swizzle(blockIdx.x, gridDim.x);

    if (blk >= TRI_PIX_BLOCKS) {
        float s0 = 0.f, s1 = 0.f;
        for (int i = threadIdx.x; i < PREP_BLOCKS; i += blockDim.x) {
            s0 += partials[2 * i];
            s1 += partials[2 * i + 1];
        }
#pragma unroll
        for (int off = 32; off > 0; off >>= 1) {
            s0 += __shfl_down(s0, off, 64);
            s1 += __shfl_down(s1, off, 64);
        }
        __shared__ float sh0[4], sh1[4];
        int wid = threadIdx.x >> 6, lane = threadIdx.x & 63;
        if (lane == 0) { sh0[wid] = s0; sh1[wid] = s1; }
        __syncthreads();
        if (threadIdx.x == 0) {
            s0 = sh0[0] + sh0[1] + sh0[2] + sh0[3];
            s1 = sh1[0] + sh1[1] + sh1[2] + sh1[3];
            const float invN = 1.0f / (float)(NUM * 3 * DIM * DIM * (DIM - 1));
            *loss = (1e-4f * s0 + 10.0f * s1) * invN;
        }
        return;
    }

    int tp = blk * blockDim.x + threadIdx.x;
    const int HP = HW / 2;
    int b = tp / HP;
    int p = (tp - b * HP) * 2;

    const float* im = img + (size_t)b * 3 * HW + p;
    f32x2 rr = __builtin_nontemporal_load((const f32x2*)(im));
    f32x2 gg = __builtin_nontemporal_load((const f32x2*)(im + HW));
    f32x2 bb = __builtin_nontemporal_load((const f32x2*)(im + 2 * HW));

    float a0, a1, a2, c0, c1, c2;
    trilerp_one(tex, b, rr.x, gg.x, bb.x, &a0, &a1, &a2);
    trilerp_one(tex, b, rr.y, gg.y, bb.y, &c0, &c1, &c2);

    f32x2 o0, o1, o2;
    o0.x = a0; o0.y = c0;
    o1.x = a1; o1.y = c1;
    o2.x = a2; o2.y = c2;

    float* o = out + (size_t)b * 3 * HW + p;
    __builtin_nontemporal_store(o0, (f32x2*)(o));
    __builtin_nontemporal_store(o1, (f32x2*)(o + HW));
    __builtin_nontemporal_store(o2, (f32x2*)(o + 2 * HW));
}

// ---------------------------------------------------------------------------
// Fallback path (ws too small).
// ---------------------------------------------------------------------------
__global__ void tvmn_atomic_kernel(const float* __restrict__ luts,
                                   float* __restrict__ loss) {
    const int total = NUM * 3 * D3;
    float s0 = 0.f, s1 = 0.f;
    for (int idx = blockIdx.x * blockDim.x + threadIdx.x; idx < total;
         idx += gridDim.x * blockDim.x) {
        int k  = idx % DIM;
        int r1 = idx / DIM;
        int j  = r1 % DIM;
        int r2 = r1 / DIM;
        int i  = r2 % DIM;
        float v = luts[idx];
        if (k < DIM - 1) {
            float dif = v - luts[idx + 1];
            float ww = (k == 0 || k == DIM - 2) ? 2.f : 1.f;
            s0 += ww * dif * dif;
            float rp = dif > 0.f ? dif : 0.f;
            s1 += (ww * rp) * (ww * rp);
        }
        if (j < DIM - 1) {
            float dif = v - luts[idx + DIM];
            float ww = (j == 0 || j == DIM - 2) ? 2.f : 1.f;
            s0 += ww * dif * dif;
            float rp = dif > 0.f ? dif : 0.f;
            s1 += (ww * rp) * (ww * rp);
        }
        if (i < DIM - 1) {
            float dif = v - luts[idx + D2];
            float ww = (i == 0 || i == DIM - 2) ? 2.f : 1.f;
            s0 += ww * dif * dif;
            float rp = dif > 0.f ? dif : 0.f;
            s1 += (ww * rp) * (ww * rp);
        }
    }
#pragma unroll
    for (int off = 32; off > 0; off >>= 1) {
        s0 += __shfl_down(s0, off, 64);
        s1 += __shfl_down(s1, off, 64);
    }
    __shared__ float sh0[4], sh1[4];
    int wid = threadIdx.x >> 6, lane = threadIdx.x & 63;
    if (lane == 0) { sh0[wid] = s0; sh1[wid] = s1; }
    __syncthreads();
    if (threadIdx.x == 0) {
        s0 = sh0[0] + sh0[1] + sh0[2] + sh0[3];
        s1 = sh1[0] + sh1[1] + sh1[2] + sh1[3];
        const float invN = 1.0f / (float)(NUM * 3 * DIM * DIM * (DIM - 1));
        atomicAdd(loss, (1e-4f * s0 + 10.0f * s1) * invN);
    }
}

__global__ void mix_lut_kernel(const float* __restrict__ w,
                               const float* __restrict__ luts,
                               float* __restrict__ d3lut,
                               float* __restrict__ loss) {
    int t = blockIdx.x * blockDim.x + threadIdx.x;
    if (t == 0) *loss = 0.f;
    if (t >= BATCH * CH3) return;
    int b = t / CH3;
    int i = t - b * CH3;
    float acc = 0.f;
#pragma unroll
    for (int n = 0; n < NUM; ++n)
        acc += w[b * NUM + n] * luts[(size_t)n * CH3 + i];
    d3lut[t] = acc;
}

__global__ void trilerp_kernel(const float* __restrict__ img,
                               const float* __restrict__ d3lut,
                               float* __restrict__ out) {
    int t = blockIdx.x * blockDim.x + threadIdx.x;
    if (t >= BATCH * HW) return;
    int b = t / HW;
    int p = t - b * HW;
    const float* im = img + (size_t)b * 3 * HW + p;
    float r = im[0], g = im[HW], bl = im[2 * HW];
    const float binsize = 1.000001f / (float)(DIM - 1);
    float fr = r / binsize, fg = g / binsize, fb = bl / binsize;
    int rid = (int)fr, gid = (int)fg, bid = (int)fb;
    float rd = fr - rid, gd = fg - gid, bd = fb - bid;
    float w000 = (1.f - rd) * (1.f - gd) * (1.f - bd);
    float w001 = rd * (1.f - gd) * (1.f - bd);
    float w010 = (1.f - rd) * gd * (1.f - bd);
    float w011 = rd * gd * (1.f - bd);
    float w100 = (1.f - rd) * (1.f - gd) * bd;
    float w101 = rd * (1.f - gd) * bd;
    float w110 = (1.f - rd) * gd * bd;
    float w111 = rd * gd * bd;
    const float* lut = d3lut + (size_t)b * CH3;
    int base = bid * D2 + gid * DIM + rid;
    float* o = out + (size_t)b * 3 * HW + p;
#pragma unroll
    for (int c = 0; c < 3; ++c) {
        const float* l = lut + (size_t)c * D3 + base;
        float v = w000 * l[0]        + w001 * l[1]
                + w010 * l[DIM]      + w011 * l[DIM + 1]
                + w100 * l[D2]       + w101 * l[D2 + 1]
                + w110 * l[D2 + DIM] + w111 * l[D2 + DIM + 1];
        o[c * HW] = v + im[c * HW];
    }
}

extern "C" void kernel_launch(void* const* d_in, const int* in_sizes, int n_in,
                              void* d_out, int out_size, void* d_ws, size_t ws_size,
                              hipStream_t stream) {
    const float* weights = (const float*)d_in[0];
    const float* luts    = (const float*)d_in[1];
    const float* img     = (const float*)d_in[2];

    float* out   = (float*)d_out;
    float* fakes = out;
    float* d3lut = out + FAKES_SIZE;
    float* loss  = out + FAKES_SIZE + D3LUT_SIZE;

    const size_t need = TEX_BYTES + (size_t)PREP_BLOCKS * 2 * sizeof(float);
    if (ws_size >= need) {
        unsigned int* tex = (unsigned int*)d_ws;
        float* partials = (float*)((char*)d_ws + TEX_BYTES);

        prep_kernel<<<PREP_BLOCKS, 256, 0, stream>>>(weights, luts, d3lut, tex,
                                                     partials);
        trilerp_cell_kernel<<<TRI_PIX_BLOCKS + 1, 256, 0, stream>>>(
            img, tex, fakes, partials, loss);
    } else {
        mix_lut_kernel<<<(BATCH * CH3 + 255) / 256, 256, 0, stream>>>(
            weights, luts, d3lut, loss);
        tvmn_atomic_kernel<<<2112, 256, 0, stream>>>(luts, loss);
        int npix = BATCH * HW;
        trilerp_kernel<<<(npix + 255) / 256, 256, 0, stream>>>(img, d3lut, fakes);
    }
}